// Round 11
// baseline (2591.050 us; speedup 1.0000x reference)
//
#include <hip/hip_runtime.h>
#include <hip/hip_bf16.h>

#define B_ 8
#define T_ 4096
#define C_ 256
#define H_ 256
#define K_ 3
#define NC 128          // time chunks (32 t each)
#define TC 32
#define WFRAG_ELEMS (24 * 32 * 64 * 8)   // [ks][ntg][lane][j] bf16

typedef __attribute__((ext_vector_type(8))) __bf16 bf16x8;
typedef __attribute__((ext_vector_type(4))) float f32x4;

__device__ __forceinline__ float sigm(float x) { return 1.0f / (1.0f + __expf(-x)); }

__device__ __forceinline__ ushort f2bf(float f) {
    union { float f; unsigned u; } v; v.f = f;
    return (ushort)((v.u + 0x7FFFu + ((v.u >> 16) & 1u)) >> 16);
}
__device__ __forceinline__ float bf2f(ushort u) {
    union { unsigned u; float f; } v; v.u = ((unsigned)u) << 16; return v.f;
}
__device__ __forceinline__ unsigned cvt_pk_bf16(float lo, float hi) {
    unsigned r;
    asm("v_cvt_pk_bf16_f32 %0, %1, %2" : "=v"(r) : "v"(lo), "v"(hi));
    return r;
}
__device__ __forceinline__ unsigned long long pack2(unsigned lo, unsigned hi) {
    return (unsigned long long)lo | ((unsigned long long)hi << 32);
}

// Gather f_w,z_w into B-fragment-linear bf16 layout; also zero the sync region
// (abFlag 1MB + uPack 2MB) every call so graph replays are deterministic.
__global__ __launch_bounds__(256) void wfrag_kernel(const float* __restrict__ fw,
                                                    const float* __restrict__ zw,
                                                    ushort* __restrict__ wfrag,
                                                    uint4* __restrict__ zbase) {
    int gid = blockIdx.x * 256 + threadIdx.x;
    if (gid < 196608) zbase[gid] = make_uint4(0, 0, 0, 0);   // 3 MB
    if (gid >= WFRAG_ELEMS) return;
    int j   = gid & 7;
    int l   = (gid >> 3) & 63;
    int ntg = (gid >> 9) & 31;
    int ks  = gid >> 14;
    int n = ntg * 16 + (l & 15);
    int kappa = ks * 32 + (l >> 4) * 8 + j;
    int k = kappa >> 8, c = kappa & 255;
    const float* w = (n < 256) ? fw : zw;
    int h = n & 255;
    wfrag[gid] = f2bf(w[(h * C_ + c) * K_ + k]);
}

__device__ __forceinline__ void bload(const ushort* wb, int ks, const int (&ntg)[4],
                                      bf16x8 (&dst)[4]) {
#pragma unroll
    for (int ni = 0; ni < 4; ++ni)
        dst[ni] = *(const bf16x8*)(wb + (size_t)ks * 16384 + (size_t)ntg[ni] * 512);
}

__device__ __forceinline__ void conv_step(const char* smem, int ks, int lr, int lg,
                                          const bf16x8 (&bfr)[4], f32x4 (&acc)[4][4]) {
    const int k = ks >> 3;
    const int cb = ((ks & 7) * 32 + lg * 8) * 2;
    bf16x8 afr[4];
#pragma unroll
    for (int mi = 0; mi < 4; ++mi) {
        int row = mi * 16 + lr + k;
        afr[mi] = *(const bf16x8*)(smem + row * 512 + (cb ^ ((row & 7) << 4)));
    }
#pragma unroll
    for (int ni = 0; ni < 4; ++ni)
#pragma unroll
        for (int mi = 0; mi < 4; ++mi)
            acc[mi][ni] = __builtin_amdgcn_mfma_f32_16x16x32_bf16(afr[mi], bfr[ni], acc[mi][ni], 0, 0, 0);
}

// ---------------------------------------------------------------------------
// Single fused kernel (normal launch): conv(f,z) + gates + in-LDS chunk scan,
// then per-(b,h) decoupled handoff:
//   every block release-publishes its chunks' local affine (a,b) per h;
//   block bx==0 of each b chains u_{c+1} = a_c + b_c*u_c (batch-8 loads) and
//   release-publishes u_c per chunk; all blocks acquire-poll their own u and
//   apply out = A + P*u from their LDS buf. All spins bounded.
// ---------------------------------------------------------------------------
__global__ __launch_bounds__(512, 4) void fused_kernel(const float* __restrict__ x,
                                                       const ushort* __restrict__ wfrag,
                                                       const float* __restrict__ fb,
                                                       const float* __restrict__ zb,
                                                       const float* __restrict__ init_f,
                                                       const float* __restrict__ init_z,
                                                       unsigned long long* __restrict__ abPack,
                                                       unsigned* __restrict__ abFlag,
                                                       unsigned long long* __restrict__ uPack,
                                                       float* __restrict__ out) {
    __shared__ __align__(16) char smem[65536];   // union: xs 66x512B | buf 64x256 uint
    unsigned* buf = (unsigned*)smem;

    const int b = blockIdx.y;
    const int t0 = blockIdx.x * 64;
    const int tid = threadIdx.x;

    // ---- stage x[b, t0-1 .. t0+64, :] as swizzled bf16 ----
    if (blockIdx.x == 0 || blockIdx.x == gridDim.x - 1) {
        for (int idx = tid; idx < 66 * 64; idx += 512) {
            int row = idx >> 6;
            int c4 = (idx & 63) * 4;
            int t = t0 - 1 + row;
            float4 v = make_float4(0.f, 0.f, 0.f, 0.f);
            if (t >= 0 && t < T_) v = *(const float4*)(x + ((size_t)(b * T_ + t)) * C_ + c4);
            uint2 w2 = make_uint2(cvt_pk_bf16(v.x, v.y), cvt_pk_bf16(v.z, v.w));
            *(uint2*)(smem + row * 512 + ((c4 * 2) ^ ((row & 7) << 4))) = w2;
        }
    } else {
        for (int idx = tid; idx < 66 * 64; idx += 512) {
            int row = idx >> 6;
            int c4 = (idx & 63) * 4;
            int t = t0 - 1 + row;
            float4 v = *(const float4*)(x + ((size_t)(b * T_ + t)) * C_ + c4);
            uint2 w2 = make_uint2(cvt_pk_bf16(v.x, v.y), cvt_pk_bf16(v.z, v.w));
            *(uint2*)(smem + row * 512 + ((c4 * 2) ^ ((row & 7) << 4))) = w2;
        }
    }
    __syncthreads();

    const int wv = tid >> 6;
    const int l  = tid & 63;
    const int lr = l & 15;
    const int lg = l >> 4;
    const int h0 = wv * 32;

    f32x4 acc[4][4];
#pragma unroll
    for (int ni = 0; ni < 4; ++ni) {
        float bv = (ni < 2 ? fb : zb)[h0 + (ni & 1) * 16 + lr];
        f32x4 bvv = {bv, bv, bv, bv};
#pragma unroll
        for (int mi = 0; mi < 4; ++mi) acc[mi][ni] = bvv;
    }

    const ushort* wb = wfrag + (size_t)l * 8;
    int ntg_[4];
#pragma unroll
    for (int ni = 0; ni < 4; ++ni)
        ntg_[ni] = (ni < 2) ? (wv * 2 + ni) : (16 + wv * 2 + ni - 2);

    // ---- conv with ping-pong B prefetch (R9-proven schedule) ----
    bf16x8 ba[4], bb[4];
    bload(wb, 0, ntg_, ba);
#pragma unroll 1
    for (int ks = 0; ks < 24; ks += 2) {
        bload(wb, ks + 1, ntg_, bb);
        conv_step(smem, ks, lr, lg, ba, acc);
        if (ks + 2 < 24) bload(wb, ks + 2, ntg_, ba);
        conv_step(smem, ks + 1, lr, lg, bb, acc);
    }

    // ---- epilogue: sigmoid + pack {a,f} for both chunks into buf[64][256] ----
    __syncthreads();                       // xs dead; buf aliases it
#pragma unroll
    for (int mi = 0; mi < 4; ++mi) {
#pragma unroll
        for (int ni = 0; ni < 2; ++ni) {
            const int h = h0 + ni * 16 + lr;
#pragma unroll
            for (int r = 0; r < 4; ++r) {
                float fv = sigm(acc[mi][ni][r]);
                float av = sigm(acc[mi][ni + 2][r]) * (1.0f - fv);
                int tl = (mi & 1) * 16 + lg * 4 + r;          // t within chunk
                int trow = (mi >> 1) * 32 + tl;               // buf row
                buf[trow * 256 + (h ^ ((tl << 2) & 31))] = cvt_pk_bf16(av, fv);
            }
        }
    }
    __syncthreads();

    // ---- per-chunk scan ({A,P} in place in buf) + publish local affine ----
    const int ch = tid >> 8;
    const int h = tid & 255;
    const int chunk = blockIdx.x * 2 + ch;
    const size_t sidx = ((size_t)b * NC + chunk) * H_ + h;
    {
        unsigned* bp = buf + ch * 32 * 256;
        unsigned u = bp[h];
        float A = bf2f((ushort)(u & 0xffff));
        float Pp = 1.0f;
        float f_prev = bf2f((ushort)(u >> 16));
        bp[h] = cvt_pk_bf16(A, Pp);
#pragma unroll 8
        for (int j = 1; j < TC; ++j) {
            const int off = j * 256 + (h ^ ((j << 2) & 31));
            u = bp[off];
            float a = bf2f((ushort)(u & 0xffff));
            float f = bf2f((ushort)(u >> 16));
            A = fmaf(f_prev, A, a);
            Pp *= f_prev;
            f_prev = f;
            bp[off] = cvt_pk_bf16(A, Pp);
        }
        // local map on seam-scaled state: u_{c+1} = a_c + b_c * u_c
        float a_c = f_prev * A;
        float b_c = f_prev * Pp;
        __hip_atomic_store(&abPack[sidx], pack2(__float_as_uint(a_c), __float_as_uint(b_c)),
                           __ATOMIC_RELAXED, __HIP_MEMORY_SCOPE_AGENT);
        __hip_atomic_store(&abFlag[sidx], 1u, __ATOMIC_RELEASE, __HIP_MEMORY_SCOPE_AGENT);
    }

    // ---- combiner: block bx==0 of each b chains across all 128 chunks ----
    if (blockIdx.x == 0 && tid < 256) {
        float f0 = sigm(init_f[b * H_ + h]);
        float z0 = sigm(init_z[b * H_ + h]);
        float s0 = z0 * (1.0f - f0);
        out[(size_t)b * (T_ + 1) * H_ + h] = s0;
        float uv = f0 * s0;                      // u_0
        const size_t base = (size_t)b * NC * H_ + h;
#pragma unroll 1
        for (int c0 = 0; c0 < NC; c0 += 8) {
            // wait for 8 locals (batched, address-independent loads)
            int it = 0;
            for (;;) {
                unsigned f = 1u;
#pragma unroll
                for (int k = 0; k < 8; ++k)
                    f &= __hip_atomic_load(&abFlag[base + (size_t)(c0 + k) * H_],
                                           __ATOMIC_ACQUIRE, __HIP_MEMORY_SCOPE_AGENT);
                if (f == 1u) break;
                __builtin_amdgcn_s_sleep(2);
                if (++it > (1 << 22)) break;
            }
            unsigned long long qs[8];
#pragma unroll
            for (int k = 0; k < 8; ++k)
                qs[k] = __hip_atomic_load(&abPack[base + (size_t)(c0 + k) * H_],
                                          __ATOMIC_RELAXED, __HIP_MEMORY_SCOPE_AGENT);
#pragma unroll
            for (int k = 0; k < 8; ++k) {
                __hip_atomic_store(&uPack[base + (size_t)(c0 + k) * H_],
                                   pack2(__float_as_uint(uv), 1u),
                                   __ATOMIC_RELEASE, __HIP_MEMORY_SCOPE_AGENT);
                float a = __uint_as_float((unsigned)qs[k]);
                float bc = __uint_as_float((unsigned)(qs[k] >> 32));
                uv = fmaf(bc, uv, a);
            }
        }
    }

    // ---- apply: poll own chunk's u, then out = A + P*u from LDS ----
    {
        unsigned long long q;
        int it = 0;
        for (;;) {
            q = __hip_atomic_load(&uPack[sidx], __ATOMIC_ACQUIRE, __HIP_MEMORY_SCOPE_AGENT);
            if ((unsigned)(q >> 32) == 1u) break;
            __builtin_amdgcn_s_sleep(2);
            if (++it > (1 << 22)) break;
        }
        const float uv = __uint_as_float((unsigned)q);
        const unsigned* bp = buf + ch * 32 * 256;
        float* op = out + ((size_t)b * (T_ + 1) + chunk * TC + 1) * H_ + h;
#pragma unroll 8
        for (int j = 0; j < TC; ++j) {
            unsigned w = bp[j * 256 + (h ^ ((j << 2) & 31))];
            op[(size_t)j * H_] = fmaf(bf2f((ushort)(w >> 16)), uv, bf2f((ushort)(w & 0xffff)));
        }
    }
}

extern "C" void kernel_launch(void* const* d_in, const int* in_sizes, int n_in,
                              void* d_out, int out_size, void* d_ws, size_t ws_size,
                              hipStream_t stream) {
    const float* inputs = (const float*)d_in[0];   // [B,T,C]
    const float* init_f = (const float*)d_in[1];   // [B,H]
    const float* init_z = (const float*)d_in[2];   // [B,H]
    const float* f_w    = (const float*)d_in[3];   // [H,C,K]
    const float* f_b    = (const float*)d_in[4];   // [H]
    const float* z_w    = (const float*)d_in[5];   // [H,C,K]
    const float* z_b    = (const float*)d_in[6];   // [H]
    float* out = (float*)d_out;                    // [B,T+1,H]

    // ws layout (bytes):
    //   0        wfrag   768 KB
    //   786432   abPack  2 MB  (ull per (b,chunk,h): {a,b} floats)
    //   2883584  abFlag  1 MB  (uint)   <- zeroed every call
    //   3932160  uPack   2 MB  (ull: {u float, magic}) <- zeroed every call
    ushort* wfrag = (ushort*)d_ws;
    unsigned long long* abPack = (unsigned long long*)((char*)d_ws + 786432);
    unsigned* abFlag           = (unsigned*)((char*)d_ws + 2883584);
    unsigned long long* uPack  = (unsigned long long*)((char*)d_ws + 3932160);
    uint4* zbase               = (uint4*)((char*)d_ws + 2883584);   // 3 MB zero region

    wfrag_kernel<<<(WFRAG_ELEMS + 255) / 256, 256, 0, stream>>>(f_w, z_w, wfrag, zbase);

    dim3 cgrid(T_ / 64, B_, 1);
    fused_kernel<<<cgrid, 512, 0, stream>>>(inputs, wfrag, f_b, z_b, init_f, init_z,
                                            abPack, abFlag, uPack, out);
}

// Round 12
// 71.463 us; speedup vs baseline: 36.2572x; 36.2572x over previous
//
#include <hip/hip_runtime.h>
#include <hip/hip_bf16.h>

#define B_ 8
#define T_ 4096
#define C_ 256
#define H_ 256
#define K_ 3
#define NC 128          // time chunks (32 t each)
#define TC 32
#define WFRAG_ELEMS (24 * 32 * 64 * 8)   // [ks][ntg][lane][j] bf16

typedef __attribute__((ext_vector_type(8))) __bf16 bf16x8;
typedef __attribute__((ext_vector_type(4))) float f32x4;

__device__ __forceinline__ float sigm(float x) { return 1.0f / (1.0f + __expf(-x)); }

__device__ __forceinline__ ushort f2bf(float f) {
    union { float f; unsigned u; } v; v.f = f;
    return (ushort)((v.u + 0x7FFFu + ((v.u >> 16) & 1u)) >> 16);
}
__device__ __forceinline__ float bf2f(ushort u) {
    union { unsigned u; float f; } v; v.u = ((unsigned)u) << 16; return v.f;
}
__device__ __forceinline__ unsigned cvt_pk_bf16(float lo, float hi) {
    unsigned r;
    asm("v_cvt_pk_bf16_f32 %0, %1, %2" : "=v"(r) : "v"(lo), "v"(hi));
    return r;
}
__device__ __forceinline__ unsigned long long pack2(unsigned lo, unsigned hi) {
    return (unsigned long long)lo | ((unsigned long long)hi << 32);
}

// Gather f_w,z_w into B-fragment-linear bf16 layout; zero the 8 abCnt counters.
__global__ __launch_bounds__(256) void wfrag_kernel(const float* __restrict__ fw,
                                                    const float* __restrict__ zw,
                                                    ushort* __restrict__ wfrag,
                                                    unsigned* __restrict__ abCnt) {
    int gid = blockIdx.x * 256 + threadIdx.x;
    if (gid < 8)
        __hip_atomic_store(&abCnt[gid], 0u, __ATOMIC_RELAXED, __HIP_MEMORY_SCOPE_AGENT);
    if (gid >= WFRAG_ELEMS) return;
    int j   = gid & 7;
    int l   = (gid >> 3) & 63;
    int ntg = (gid >> 9) & 31;
    int ks  = gid >> 14;
    int n = ntg * 16 + (l & 15);
    int kappa = ks * 32 + (l >> 4) * 8 + j;
    int k = kappa >> 8, c = kappa & 255;
    const float* w = (n < 256) ? fw : zw;
    int h = n & 255;
    wfrag[gid] = f2bf(w[(h * C_ + c) * K_ + k]);
}

__device__ __forceinline__ void bload(const ushort* wb, int ks, const int (&ntg)[4],
                                      bf16x8 (&dst)[4]) {
#pragma unroll
    for (int ni = 0; ni < 4; ++ni)
        dst[ni] = *(const bf16x8*)(wb + (size_t)ks * 16384 + (size_t)ntg[ni] * 512);
}

__device__ __forceinline__ void conv_step(const char* smem, int ks, int lr, int lg,
                                          const bf16x8 (&bfr)[4], f32x4 (&acc)[4][4]) {
    const int k = ks >> 3;
    const int cb = ((ks & 7) * 32 + lg * 8) * 2;
    bf16x8 afr[4];
#pragma unroll
    for (int mi = 0; mi < 4; ++mi) {
        int row = mi * 16 + lr + k;
        afr[mi] = *(const bf16x8*)(smem + row * 512 + (cb ^ ((row & 7) << 4)));
    }
#pragma unroll
    for (int ni = 0; ni < 4; ++ni)
#pragma unroll
        for (int mi = 0; mi < 4; ++mi)
            acc[mi][ni] = __builtin_amdgcn_mfma_f32_16x16x32_bf16(afr[mi], bfr[ni], acc[mi][ni], 0, 0, 0);
}

// ---------------------------------------------------------------------------
// Single fused kernel: conv(f,z) + gates + in-LDS chunk scan + self-combine +
// apply. Sync protocol (minimal fences):
//   - each thread publishes its chunk's (a_c,b_c) via ONE relaxed agent 8B
//     atomic store (routes to L3; completion drained by __syncthreads)
//   - ONE release fetch_add per block on abCnt[b]
//   - one thread polls abCnt[b]==64 (bounded), then the whole block chains
//     the prefix c=0..2bx itself (double-buffered batch-8 relaxed loads)
//   - u handed to apply threads through buf row-0 slots (j=0 applied inline)
// ---------------------------------------------------------------------------
__global__ __launch_bounds__(512, 4) void fused_kernel(const float* __restrict__ x,
                                                       const ushort* __restrict__ wfrag,
                                                       const float* __restrict__ fb,
                                                       const float* __restrict__ zb,
                                                       const float* __restrict__ init_f,
                                                       const float* __restrict__ init_z,
                                                       unsigned long long* __restrict__ abPack,
                                                       unsigned* __restrict__ abCnt,
                                                       float* __restrict__ out) {
    __shared__ __align__(16) char smem[65536];   // union: xs 66x512B | buf 64x256 uint
    unsigned* buf = (unsigned*)smem;

    const int b = blockIdx.y;
    const int bx = blockIdx.x;
    const int t0 = bx * 64;
    const int tid = threadIdx.x;

    // ---- stage x[b, t0-1 .. t0+64, :] as swizzled bf16 ----
    if (bx == 0 || bx == gridDim.x - 1) {
        for (int idx = tid; idx < 66 * 64; idx += 512) {
            int row = idx >> 6;
            int c4 = (idx & 63) * 4;
            int t = t0 - 1 + row;
            float4 v = make_float4(0.f, 0.f, 0.f, 0.f);
            if (t >= 0 && t < T_) v = *(const float4*)(x + ((size_t)(b * T_ + t)) * C_ + c4);
            uint2 w2 = make_uint2(cvt_pk_bf16(v.x, v.y), cvt_pk_bf16(v.z, v.w));
            *(uint2*)(smem + row * 512 + ((c4 * 2) ^ ((row & 7) << 4))) = w2;
        }
    } else {
        for (int idx = tid; idx < 66 * 64; idx += 512) {
            int row = idx >> 6;
            int c4 = (idx & 63) * 4;
            int t = t0 - 1 + row;
            float4 v = *(const float4*)(x + ((size_t)(b * T_ + t)) * C_ + c4);
            uint2 w2 = make_uint2(cvt_pk_bf16(v.x, v.y), cvt_pk_bf16(v.z, v.w));
            *(uint2*)(smem + row * 512 + ((c4 * 2) ^ ((row & 7) << 4))) = w2;
        }
    }
    __syncthreads();

    const int wv = tid >> 6;
    const int l  = tid & 63;
    const int lr = l & 15;
    const int lg = l >> 4;
    const int h0 = wv * 32;

    f32x4 acc[4][4];
#pragma unroll
    for (int ni = 0; ni < 4; ++ni) {
        float bv = (ni < 2 ? fb : zb)[h0 + (ni & 1) * 16 + lr];
        f32x4 bvv = {bv, bv, bv, bv};
#pragma unroll
        for (int mi = 0; mi < 4; ++mi) acc[mi][ni] = bvv;
    }

    const ushort* wb = wfrag + (size_t)l * 8;
    int ntg_[4];
#pragma unroll
    for (int ni = 0; ni < 4; ++ni)
        ntg_[ni] = (ni < 2) ? (wv * 2 + ni) : (16 + wv * 2 + ni - 2);

    // ---- conv with ping-pong B prefetch (R9-proven schedule) ----
    bf16x8 ba[4], bb[4];
    bload(wb, 0, ntg_, ba);
#pragma unroll 1
    for (int ks = 0; ks < 24; ks += 2) {
        bload(wb, ks + 1, ntg_, bb);
        conv_step(smem, ks, lr, lg, ba, acc);
        if (ks + 2 < 24) bload(wb, ks + 2, ntg_, ba);
        conv_step(smem, ks + 1, lr, lg, bb, acc);
    }

    // ---- epilogue: sigmoid + pack {a,f} for both chunks into buf[64][256] ----
    __syncthreads();                       // xs dead; buf aliases it
#pragma unroll
    for (int mi = 0; mi < 4; ++mi) {
#pragma unroll
        for (int ni = 0; ni < 2; ++ni) {
            const int h = h0 + ni * 16 + lr;
#pragma unroll
            for (int r = 0; r < 4; ++r) {
                float fv = sigm(acc[mi][ni][r]);
                float av = sigm(acc[mi][ni + 2][r]) * (1.0f - fv);
                int tl = (mi & 1) * 16 + lg * 4 + r;          // t within chunk
                int trow = (mi >> 1) * 32 + tl;               // buf row
                buf[trow * 256 + (h ^ ((tl << 2) & 31))] = cvt_pk_bf16(av, fv);
            }
        }
    }
    __syncthreads();

    // ---- per-chunk scan ({A,P} in place in buf) + publish (a_c,b_c) relaxed ----
    const int ch = tid >> 8;
    const int hh = tid & 255;
    {
        const int chunk = bx * 2 + ch;
        unsigned* bp = buf + ch * 32 * 256;
        unsigned u = bp[hh];
        float A = bf2f((ushort)(u & 0xffff));
        float Pp = 1.0f;
        float f_prev = bf2f((ushort)(u >> 16));
        bp[hh] = cvt_pk_bf16(A, Pp);
#pragma unroll 8
        for (int j = 1; j < TC; ++j) {
            const int off = j * 256 + (hh ^ ((j << 2) & 31));
            u = bp[off];
            float a = bf2f((ushort)(u & 0xffff));
            float f = bf2f((ushort)(u >> 16));
            A = fmaf(f_prev, A, a);
            Pp *= f_prev;
            f_prev = f;
            bp[off] = cvt_pk_bf16(A, Pp);
        }
        float a_c = f_prev * A;     // u_{c+1} = a_c + b_c * u_c
        float b_c = f_prev * Pp;
        __hip_atomic_store(&abPack[((size_t)b * NC + chunk) * H_ + hh],
                           pack2(__float_as_uint(a_c), __float_as_uint(b_c)),
                           __ATOMIC_RELAXED, __HIP_MEMORY_SCOPE_AGENT);
    }
    __syncthreads();               // drains vmcnt: all abPack stores complete at L3

    // ---- one release add + bounded poll (single thread) ----
    if (tid == 0) {
        __hip_atomic_fetch_add(&abCnt[b], 1u, __ATOMIC_RELEASE, __HIP_MEMORY_SCOPE_AGENT);
        int it = 0;
        while (__hip_atomic_load(&abCnt[b], __ATOMIC_ACQUIRE, __HIP_MEMORY_SCOPE_AGENT) != 64u) {
            __builtin_amdgcn_s_sleep(4);
            if (++it > (1 << 20)) break;   // bounded: degrade, never hang
        }
    }
    __syncthreads();

    // ---- self-combine: chain prefix c = 0..2bx, capture u at 2bx and 2bx+1 ----
    if (tid < 256) {
        const int h = tid;
        float f0 = sigm(init_f[b * H_ + h]);
        float z0 = sigm(init_z[b * H_ + h]);
        float s0 = z0 * (1.0f - f0);
        if (bx == 0) out[(size_t)b * (T_ + 1) * H_ + h] = s0;
        float uv = f0 * s0;                 // u_0
        float u0v = uv;
        const int last = 2 * bx + 1;        // chain steps c = 0..last-1
        const size_t base = (size_t)b * NC * H_ + h;
        unsigned long long qa[8], qb[8];
#define LB(Q, C0)                                                                     \
        {                                                                             \
            _Pragma("unroll")                                                         \
            for (int k2 = 0; k2 < 8; ++k2) {                                          \
                int cc = (C0) + k2; cc = cc < NC ? cc : NC - 1;                       \
                Q[k2] = __hip_atomic_load(&abPack[base + (size_t)cc * H_],            \
                                          __ATOMIC_RELAXED, __HIP_MEMORY_SCOPE_AGENT);\
            }                                                                         \
        }
        LB(qa, 0);
#pragma unroll 1
        for (int c0 = 0; c0 < last; c0 += 16) {
            if (c0 + 8 < last) LB(qb, c0 + 8);
#pragma unroll
            for (int k2 = 0; k2 < 8; ++k2) {
                int c = c0 + k2;
                if (c < last) {
                    if (c == last - 1) u0v = uv;
                    uv = fmaf(__uint_as_float((unsigned)(qa[k2] >> 32)), uv,
                              __uint_as_float((unsigned)qa[k2]));
                }
            }
            if (c0 + 16 < last) LB(qa, c0 + 16);
#pragma unroll
            for (int k2 = 0; k2 < 8; ++k2) {
                int c = c0 + 8 + k2;
                if (c < last) {
                    if (c == last - 1) u0v = uv;
                    uv = fmaf(__uint_as_float((unsigned)(qb[k2] >> 32)), uv,
                              __uint_as_float((unsigned)qb[k2]));
                }
            }
        }
        float u1v = uv;                     // u at c = 2bx+1

        // j=0 apply for both chunks, then stash u in the row-0 slots
        unsigned w0 = buf[h];
        out[((size_t)b * (T_ + 1) + (2 * bx) * TC + 1) * H_ + h] =
            fmaf(bf2f((ushort)(w0 >> 16)), u0v, bf2f((ushort)(w0 & 0xffff)));
        buf[h] = __float_as_uint(u0v);
        unsigned w1 = buf[32 * 256 + h];
        out[((size_t)b * (T_ + 1) + (2 * bx + 1) * TC + 1) * H_ + h] =
            fmaf(bf2f((ushort)(w1 >> 16)), u1v, bf2f((ushort)(w1 & 0xffff)));
        buf[32 * 256 + h] = __float_as_uint(u1v);
#undef LB
    }
    __syncthreads();

    // ---- apply j = 1..31 from LDS: out = A + P*u ----
    {
        const int chunk = bx * 2 + ch;
        const float uv = __uint_as_float(buf[ch * 32 * 256 + hh]);
        const unsigned* bp = buf + ch * 32 * 256;
        float* op = out + ((size_t)b * (T_ + 1) + chunk * TC + 1) * H_ + hh;
#pragma unroll 8
        for (int j = 1; j < TC; ++j) {
            unsigned w = bp[j * 256 + (hh ^ ((j << 2) & 31))];
            op[(size_t)j * H_] = fmaf(bf2f((ushort)(w >> 16)), uv, bf2f((ushort)(w & 0xffff)));
        }
    }
}

extern "C" void kernel_launch(void* const* d_in, const int* in_sizes, int n_in,
                              void* d_out, int out_size, void* d_ws, size_t ws_size,
                              hipStream_t stream) {
    const float* inputs = (const float*)d_in[0];   // [B,T,C]
    const float* init_f = (const float*)d_in[1];   // [B,H]
    const float* init_z = (const float*)d_in[2];   // [B,H]
    const float* f_w    = (const float*)d_in[3];   // [H,C,K]
    const float* f_b    = (const float*)d_in[4];   // [H]
    const float* z_w    = (const float*)d_in[5];   // [H,C,K]
    const float* z_b    = (const float*)d_in[6];   // [H]
    float* out = (float*)d_out;                    // [B,T+1,H]

    // ws: wfrag 768KB | abPack 2MB (ull per (b,chunk,h)) | abCnt 32B (zeroed/call)
    ushort* wfrag              = (ushort*)d_ws;
    unsigned long long* abPack = (unsigned long long*)((char*)d_ws + 786432);
    unsigned* abCnt            = (unsigned*)((char*)d_ws + 786432 + 2097152);

    wfrag_kernel<<<(WFRAG_ELEMS + 255) / 256, 256, 0, stream>>>(f_w, z_w, wfrag, abCnt);

    dim3 cgrid(T_ / 64, B_, 1);
    fused_kernel<<<cgrid, 512, 0, stream>>>(inputs, wfrag, f_b, z_b, init_f, init_z,
                                            abPack, abCnt, out);
}

// Round 13
// 65.144 us; speedup vs baseline: 39.7742x; 1.0970x over previous
//
#include <hip/hip_runtime.h>
#include <hip/hip_bf16.h>

#define B_ 8
#define T_ 4096
#define C_ 256
#define H_ 256
#define K_ 3
#define NC 128          // time chunks (32 t each)
#define TC 32
#define WFRAG_ELEMS (24 * 32 * 64 * 8)   // [ks][ntg][lane][j] bf16

typedef __attribute__((ext_vector_type(8))) __bf16 bf16x8;
typedef __attribute__((ext_vector_type(4))) float f32x4;

__device__ __forceinline__ float sigm(float x) { return 1.0f / (1.0f + __expf(-x)); }

__device__ __forceinline__ ushort f2bf(float f) {
    union { float f; unsigned u; } v; v.f = f;
    return (ushort)((v.u + 0x7FFFu + ((v.u >> 16) & 1u)) >> 16);
}
__device__ __forceinline__ float bf2f(ushort u) {
    union { unsigned u; float f; } v; v.u = ((unsigned)u) << 16; return v.f;
}
__device__ __forceinline__ unsigned cvt_pk_bf16(float lo, float hi) {
    unsigned r;
    asm("v_cvt_pk_bf16_f32 %0, %1, %2" : "=v"(r) : "v"(lo), "v"(hi));
    return r;
}

// Gather f_w,z_w into B-fragment-linear bf16 layout for mfma_f32_16x16x32_bf16.
__global__ __launch_bounds__(256) void wfrag_kernel(const float* __restrict__ fw,
                                                    const float* __restrict__ zw,
                                                    ushort* __restrict__ wfrag) {
    int idx = blockIdx.x * 256 + threadIdx.x;
    if (idx >= WFRAG_ELEMS) return;
    int j   = idx & 7;
    int l   = (idx >> 3) & 63;
    int ntg = (idx >> 9) & 31;
    int ks  = idx >> 14;
    int n = ntg * 16 + (l & 15);
    int kappa = ks * 32 + (l >> 4) * 8 + j;
    int k = kappa >> 8, c = kappa & 255;
    const float* w = (n < 256) ? fw : zw;
    int h = n & 255;
    wfrag[idx] = f2bf(w[(h * C_ + c) * K_ + k]);
}

__device__ __forceinline__ void bload(const ushort* wb, int ks, const int (&ntg)[4],
                                      bf16x8 (&dst)[4]) {
#pragma unroll
    for (int ni = 0; ni < 4; ++ni)
        dst[ni] = *(const bf16x8*)(wb + (size_t)ks * 16384 + (size_t)ntg[ni] * 512);
}

__device__ __forceinline__ void conv_step(const char* smem, int ks, int lr, int lg,
                                          const bf16x8 (&bfr)[4], f32x4 (&acc)[4][4]) {
    const int k = ks >> 3;
    const int cb = ((ks & 7) * 32 + lg * 8) * 2;
    bf16x8 afr[4];
#pragma unroll
    for (int mi = 0; mi < 4; ++mi) {
        int row = mi * 16 + lr + k;
        afr[mi] = *(const bf16x8*)(smem + row * 512 + (cb ^ ((row & 7) << 4)));
    }
#pragma unroll
    for (int ni = 0; ni < 4; ++ni)
#pragma unroll
        for (int mi = 0; mi < 4; ++mi)
            acc[mi][ni] = __builtin_amdgcn_mfma_f32_16x16x32_bf16(afr[mi], bfr[ni], acc[mi][ni], 0, 0, 0);
}

// ---------------------------------------------------------------------------
// Fused conv (f and z) + gates + per-chunk affine scan (R9-proven structure).
// Writes AP (packed bf16 {A_j,P'_j}) + per-chunk map coeffs ab = {fl*A31, fl*P31}.
// ---------------------------------------------------------------------------
__global__ __launch_bounds__(512, 4) void conv_scan_kernel(const float* __restrict__ x,
                                                           const ushort* __restrict__ wfrag,
                                                           const float* __restrict__ fb,
                                                           const float* __restrict__ zb,
                                                           unsigned* __restrict__ AP,
                                                           float2* __restrict__ ab) {
    __shared__ __align__(16) char smem[65536];   // union: xs 66x512B | buf 64x256 uint
    unsigned* buf = (unsigned*)smem;

    const int b = blockIdx.y;
    const int t0 = blockIdx.x * 64;
    const int tid = threadIdx.x;

    // Stage x[b, t0-1 .. t0+64, :] as bf16, swizzled: byte = row*512 + ((2c) ^ ((row&7)<<4))
    if (blockIdx.x == 0 || blockIdx.x == gridDim.x - 1) {
        for (int idx = tid; idx < 66 * 64; idx += 512) {
            int row = idx >> 6;
            int c4 = (idx & 63) * 4;
            int t = t0 - 1 + row;
            float4 v = make_float4(0.f, 0.f, 0.f, 0.f);
            if (t >= 0 && t < T_) v = *(const float4*)(x + ((size_t)(b * T_ + t)) * C_ + c4);
            uint2 w2 = make_uint2(cvt_pk_bf16(v.x, v.y), cvt_pk_bf16(v.z, v.w));
            *(uint2*)(smem + row * 512 + ((c4 * 2) ^ ((row & 7) << 4))) = w2;
        }
    } else {
        for (int idx = tid; idx < 66 * 64; idx += 512) {
            int row = idx >> 6;
            int c4 = (idx & 63) * 4;
            int t = t0 - 1 + row;
            float4 v = *(const float4*)(x + ((size_t)(b * T_ + t)) * C_ + c4);
            uint2 w2 = make_uint2(cvt_pk_bf16(v.x, v.y), cvt_pk_bf16(v.z, v.w));
            *(uint2*)(smem + row * 512 + ((c4 * 2) ^ ((row & 7) << 4))) = w2;
        }
    }
    __syncthreads();

    const int wv = tid >> 6;
    const int l  = tid & 63;
    const int lr = l & 15;
    const int lg = l >> 4;
    const int h0 = wv * 32;

    f32x4 acc[4][4];
#pragma unroll
    for (int ni = 0; ni < 4; ++ni) {
        float bv = (ni < 2 ? fb : zb)[h0 + (ni & 1) * 16 + lr];
        f32x4 bvv = {bv, bv, bv, bv};
#pragma unroll
        for (int mi = 0; mi < 4; ++mi) acc[mi][ni] = bvv;
    }

    const ushort* wb = wfrag + (size_t)l * 8;
    int ntg_[4];
#pragma unroll
    for (int ni = 0; ni < 4; ++ni)
        ntg_[ni] = (ni < 2) ? (wv * 2 + ni) : (16 + wv * 2 + ni - 2);

    // Conv with ping-pong B prefetch (proven schedule).
    bf16x8 ba[4], bb[4];
    bload(wb, 0, ntg_, ba);
#pragma unroll 1
    for (int ks = 0; ks < 24; ks += 2) {
        bload(wb, ks + 1, ntg_, bb);
        conv_step(smem, ks, lr, lg, ba, acc);
        if (ks + 2 < 24) bload(wb, ks + 2, ntg_, ba);
        conv_step(smem, ks + 1, lr, lg, bb, acc);
    }

    // One-phase epilogue: sigmoid + pack {a,f} for both chunks into buf[64][256].
    __syncthreads();                       // xs dead; buf aliases it
#pragma unroll
    for (int mi = 0; mi < 4; ++mi) {
#pragma unroll
        for (int ni = 0; ni < 2; ++ni) {
            const int h = h0 + ni * 16 + lr;
#pragma unroll
            for (int r = 0; r < 4; ++r) {
                float fv = sigm(acc[mi][ni][r]);
                float av = sigm(acc[mi][ni + 2][r]) * (1.0f - fv);
                int tl = (mi & 1) * 16 + lg * 4 + r;          // t within chunk
                int trow = (mi >> 1) * 32 + tl;               // buf row
                buf[trow * 256 + (h ^ ((tl << 2) & 31))] = cvt_pk_bf16(av, fv);
            }
        }
    }
    __syncthreads();

    // Parallel per-chunk scan: all 512 threads (ch = tid>>8, h = tid&255).
    {
        const int ch = tid >> 8;
        const int h = tid & 255;
        const int chunk = blockIdx.x * 2 + ch;
        const int r0 = chunk * TC;
        const unsigned* bp = buf + ch * 32 * 256;
        unsigned* app = AP + ((size_t)b * T_ + r0) * H_ + h;
        unsigned u = bp[h];
        float A = bf2f((ushort)(u & 0xffff));
        float Pp = 1.0f;
        float f_prev = bf2f((ushort)(u >> 16));
        app[0] = cvt_pk_bf16(A, Pp);
#pragma unroll 8
        for (int j = 1; j < TC; ++j) {
            u = bp[j * 256 + (h ^ ((j << 2) & 31))];
            float a = bf2f((ushort)(u & 0xffff));
            float f = bf2f((ushort)(u >> 16));
            A = fmaf(f_prev, A, a);
            Pp *= f_prev;
            f_prev = f;
            app[(size_t)j * H_] = cvt_pk_bf16(A, Pp);
        }
        // per-chunk map on seam-scaled state: u_{c+1} = a_c + b_c * u_c
        ab[((size_t)b * NC + chunk) * H_ + h] = make_float2(f_prev * A, f_prev * Pp);
    }
}

// ---------------------------------------------------------------------------
// Chain + apply (combine folded in): block (c,b) chains u_c = prefix of the
// per-chunk affine maps (plain coalesced loads, address-independent ->
// pipelined), then applies out = A_j + P'_j * u_c for its 32 rows.
// ---------------------------------------------------------------------------
__global__ __launch_bounds__(256) void chainapply_kernel(const unsigned* __restrict__ AP,
                                                         const float2* __restrict__ ab,
                                                         const float* __restrict__ init_f,
                                                         const float* __restrict__ init_z,
                                                         float* __restrict__ out) {
    const int c = blockIdx.x;
    const int b = blockIdx.y;
    const int h = threadIdx.x;

    float f0 = sigm(init_f[b * H_ + h]);
    float z0 = sigm(init_z[b * H_ + h]);
    float s0 = z0 * (1.0f - f0);
    if (c == 0) out[(size_t)b * (T_ + 1) * H_ + h] = s0;

    float uv = f0 * s0;                              // u_0
    const float2* abp = ab + (size_t)b * NC * H_ + h;
#pragma unroll 8
    for (int cc = 0; cc < c; ++cc) {
        float2 q = abp[(size_t)cc * H_];
        uv = fmaf(q.y, uv, q.x);
    }

    const unsigned* app = AP + ((size_t)b * T_ + c * TC) * H_ + h;
    float* op = out + ((size_t)b * (T_ + 1) + c * TC + 1) * H_ + h;
#pragma unroll 8
    for (int j = 0; j < TC; ++j) {
        unsigned w = app[(size_t)j * H_];
        op[(size_t)j * H_] = fmaf(bf2f((ushort)(w >> 16)), uv, bf2f((ushort)(w & 0xffff)));
    }
}

extern "C" void kernel_launch(void* const* d_in, const int* in_sizes, int n_in,
                              void* d_out, int out_size, void* d_ws, size_t ws_size,
                              hipStream_t stream) {
    const float* inputs = (const float*)d_in[0];   // [B,T,C]
    const float* init_f = (const float*)d_in[1];   // [B,H]
    const float* init_z = (const float*)d_in[2];   // [B,H]
    const float* f_w    = (const float*)d_in[3];   // [H,C,K]
    const float* f_b    = (const float*)d_in[4];   // [H]
    const float* z_w    = (const float*)d_in[5];   // [H,C,K]
    const float* z_b    = (const float*)d_in[6];   // [H]
    float* out = (float*)d_out;                    // [B,T+1,H]

    // ws: wfrag 768KB | AP (B*T*H uint, 32MB) | ab (B*NC*H float2, 2MB)
    ushort* wfrag = (ushort*)d_ws;
    unsigned* AP  = (unsigned*)(wfrag + WFRAG_ELEMS);
    float2* ab    = (float2*)(AP + (size_t)B_ * T_ * H_);

    wfrag_kernel<<<(WFRAG_ELEMS + 255) / 256, 256, 0, stream>>>(f_w, z_w, wfrag);

    dim3 cgrid(T_ / 64, B_, 1);
    conv_scan_kernel<<<cgrid, 512, 0, stream>>>(inputs, wfrag, f_b, z_b, AP, ab);

    dim3 agrid(NC, B_, 1);
    chainapply_kernel<<<agrid, 256, 0, stream>>>(AP, ab, init_f, init_z, out);
}

// Round 14
// 64.787 us; speedup vs baseline: 39.9934x; 1.0055x over previous
//
#include <hip/hip_runtime.h>
#include <hip/hip_bf16.h>

#define B_ 8
#define T_ 4096
#define C_ 256
#define H_ 256
#define K_ 3
#define NC 128          // time chunks (32 t each)
#define TC 32
#define WFRAG_ELEMS (24 * 32 * 64 * 8)   // [ks][ntg][lane][j] bf16

typedef __attribute__((ext_vector_type(8))) __bf16 bf16x8;
typedef __attribute__((ext_vector_type(4))) float f32x4;

__device__ __forceinline__ float sigm(float x) { return 1.0f / (1.0f + __expf(-x)); }

__device__ __forceinline__ ushort f2bf(float f) {
    union { float f; unsigned u; } v; v.f = f;
    return (ushort)((v.u + 0x7FFFu + ((v.u >> 16) & 1u)) >> 16);
}
__device__ __forceinline__ float bf2f(ushort u) {
    union { unsigned u; float f; } v; v.u = ((unsigned)u) << 16; return v.f;
}
__device__ __forceinline__ unsigned cvt_pk_bf16(float lo, float hi) {
    unsigned r;
    asm("v_cvt_pk_bf16_f32 %0, %1, %2" : "=v"(r) : "v"(lo), "v"(hi));
    return r;
}

// Gather f_w,z_w into B-fragment-linear bf16 layout for mfma_f32_16x16x32_bf16.
__global__ __launch_bounds__(256) void wfrag_kernel(const float* __restrict__ fw,
                                                    const float* __restrict__ zw,
                                                    ushort* __restrict__ wfrag) {
    int idx = blockIdx.x * 256 + threadIdx.x;
    if (idx >= WFRAG_ELEMS) return;
    int j   = idx & 7;
    int l   = (idx >> 3) & 63;
    int ntg = (idx >> 9) & 31;
    int ks  = idx >> 14;
    int n = ntg * 16 + (l & 15);
    int kappa = ks * 32 + (l >> 4) * 8 + j;
    int k = kappa >> 8, c = kappa & 255;
    const float* w = (n < 256) ? fw : zw;
    int h = n & 255;
    wfrag[idx] = f2bf(w[(h * C_ + c) * K_ + k]);
}

__device__ __forceinline__ void bload(const ushort* wb, int ks, const int (&ntg)[4],
                                      bf16x8 (&dst)[4]) {
#pragma unroll
    for (int ni = 0; ni < 4; ++ni)
        dst[ni] = *(const bf16x8*)(wb + (size_t)ks * 16384 + (size_t)ntg[ni] * 512);
}

__device__ __forceinline__ void conv_step(const char* smem, int ks, int lr, int lg,
                                          const bf16x8 (&bfr)[4], f32x4 (&acc)[4][4]) {
    const int k = ks >> 3;
    const int cb = ((ks & 7) * 32 + lg * 8) * 2;
    bf16x8 afr[4];
#pragma unroll
    for (int mi = 0; mi < 4; ++mi) {
        int row = mi * 16 + lr + k;
        afr[mi] = *(const bf16x8*)(smem + row * 512 + (cb ^ ((row & 7) << 4)));
    }
    __builtin_amdgcn_s_setprio(1);
#pragma unroll
    for (int ni = 0; ni < 4; ++ni)
#pragma unroll
        for (int mi = 0; mi < 4; ++mi)
            acc[mi][ni] = __builtin_amdgcn_mfma_f32_16x16x32_bf16(afr[mi], bfr[ni], acc[mi][ni], 0, 0, 0);
    __builtin_amdgcn_s_setprio(0);
}

// ---------------------------------------------------------------------------
// Fused conv (f and z) + gates + per-chunk affine scan (R13-proven structure).
// Writes AP (packed bf16 {A_j,P'_j}) + per-chunk map coeffs ab = {fl*A31, fl*P31}.
// ---------------------------------------------------------------------------
__global__ __launch_bounds__(512, 4) void conv_scan_kernel(const float* __restrict__ x,
                                                           const ushort* __restrict__ wfrag,
                                                           const float* __restrict__ fb,
                                                           const float* __restrict__ zb,
                                                           unsigned* __restrict__ AP,
                                                           float2* __restrict__ ab) {
    __shared__ __align__(16) char smem[65536];   // union: xs 66x512B | buf 64x256 uint
    unsigned* buf = (unsigned*)smem;

    const int b = blockIdx.y;
    const int t0 = blockIdx.x * 64;
    const int tid = threadIdx.x;

    // Stage x[b, t0-1 .. t0+64, :] as bf16, swizzled: byte = row*512 + ((2c) ^ ((row&7)<<4))
    if (blockIdx.x == 0 || blockIdx.x == gridDim.x - 1) {
        for (int idx = tid; idx < 66 * 64; idx += 512) {
            int row = idx >> 6;
            int c4 = (idx & 63) * 4;
            int t = t0 - 1 + row;
            float4 v = make_float4(0.f, 0.f, 0.f, 0.f);
            if (t >= 0 && t < T_) v = *(const float4*)(x + ((size_t)(b * T_ + t)) * C_ + c4);
            uint2 w2 = make_uint2(cvt_pk_bf16(v.x, v.y), cvt_pk_bf16(v.z, v.w));
            *(uint2*)(smem + row * 512 + ((c4 * 2) ^ ((row & 7) << 4))) = w2;
        }
    } else {
        for (int idx = tid; idx < 66 * 64; idx += 512) {
            int row = idx >> 6;
            int c4 = (idx & 63) * 4;
            int t = t0 - 1 + row;
            float4 v = *(const float4*)(x + ((size_t)(b * T_ + t)) * C_ + c4);
            uint2 w2 = make_uint2(cvt_pk_bf16(v.x, v.y), cvt_pk_bf16(v.z, v.w));
            *(uint2*)(smem + row * 512 + ((c4 * 2) ^ ((row & 7) << 4))) = w2;
        }
    }
    __syncthreads();

    const int wv = tid >> 6;
    const int l  = tid & 63;
    const int lr = l & 15;
    const int lg = l >> 4;
    const int h0 = wv * 32;

    f32x4 acc[4][4];
#pragma unroll
    for (int ni = 0; ni < 4; ++ni) {
        float bv = (ni < 2 ? fb : zb)[h0 + (ni & 1) * 16 + lr];
        f32x4 bvv = {bv, bv, bv, bv};
#pragma unroll
        for (int mi = 0; mi < 4; ++mi) acc[mi][ni] = bvv;
    }

    const ushort* wb = wfrag + (size_t)l * 8;
    int ntg_[4];
#pragma unroll
    for (int ni = 0; ni < 4; ++ni)
        ntg_[ni] = (ni < 2) ? (wv * 2 + ni) : (16 + wv * 2 + ni - 2);

    // Conv with ping-pong B prefetch (proven schedule).
    bf16x8 ba[4], bb[4];
    bload(wb, 0, ntg_, ba);
#pragma unroll 1
    for (int ks = 0; ks < 24; ks += 2) {
        bload(wb, ks + 1, ntg_, bb);
        conv_step(smem, ks, lr, lg, ba, acc);
        if (ks + 2 < 24) bload(wb, ks + 2, ntg_, ba);
        conv_step(smem, ks + 1, lr, lg, bb, acc);
    }

    // One-phase epilogue: sigmoid + pack {a,f} for both chunks into buf[64][256].
    __syncthreads();                       // xs dead; buf aliases it
#pragma unroll
    for (int mi = 0; mi < 4; ++mi) {
#pragma unroll
        for (int ni = 0; ni < 2; ++ni) {
            const int h = h0 + ni * 16 + lr;
#pragma unroll
            for (int r = 0; r < 4; ++r) {
                float fv = sigm(acc[mi][ni][r]);
                float av = sigm(acc[mi][ni + 2][r]) * (1.0f - fv);
                int tl = (mi & 1) * 16 + lg * 4 + r;          // t within chunk
                int trow = (mi >> 1) * 32 + tl;               // buf row
                buf[trow * 256 + (h ^ ((tl << 2) & 31))] = cvt_pk_bf16(av, fv);
            }
        }
    }
    __syncthreads();

    // Parallel per-chunk scan: all 512 threads (ch = tid>>8, h = tid&255).
    {
        const int ch = tid >> 8;
        const int h = tid & 255;
        const int chunk = blockIdx.x * 2 + ch;
        const int r0 = chunk * TC;
        const unsigned* bp = buf + ch * 32 * 256;
        unsigned* app = AP + ((size_t)b * T_ + r0) * H_ + h;
        unsigned u = bp[h];
        float A = bf2f((ushort)(u & 0xffff));
        float Pp = 1.0f;
        float f_prev = bf2f((ushort)(u >> 16));
        app[0] = cvt_pk_bf16(A, Pp);
#pragma unroll 8
        for (int j = 1; j < TC; ++j) {
            u = bp[j * 256 + (h ^ ((j << 2) & 31))];
            float a = bf2f((ushort)(u & 0xffff));
            float f = bf2f((ushort)(u >> 16));
            A = fmaf(f_prev, A, a);
            Pp *= f_prev;
            f_prev = f;
            app[(size_t)j * H_] = cvt_pk_bf16(A, Pp);
        }
        // per-chunk map on seam-scaled state: u_{c+1} = a_c + b_c * u_c
        ab[((size_t)b * NC + chunk) * H_ + h] = make_float2(f_prev * A, f_prev * Pp);
    }
}

// ---------------------------------------------------------------------------
// Chain + apply: block p handles chunk c = perm(p) with (c>>1)%8 == p%8 so it
// lands on the same XCD (round-robin heuristic) as the conv block that wrote
// its AP slice -> AP reads hit XCD-local L2. Any bijection is correct.
// ---------------------------------------------------------------------------
__global__ __launch_bounds__(256) void chainapply_kernel(const unsigned* __restrict__ AP,
                                                         const float2* __restrict__ ab,
                                                         const float* __restrict__ init_f,
                                                         const float* __restrict__ init_z,
                                                         float* __restrict__ out) {
    const int p = blockIdx.x;
    const int tq = p >> 3;
    const int c = 16 * (tq >> 1) + 2 * (p & 7) + (tq & 1);   // bijective, (c>>1)%8==p%8
    const int b = blockIdx.y;
    const int h = threadIdx.x;

    float f0 = sigm(init_f[b * H_ + h]);
    float z0 = sigm(init_z[b * H_ + h]);
    float s0 = z0 * (1.0f - f0);
    if (c == 0) out[(size_t)b * (T_ + 1) * H_ + h] = s0;

    float uv = f0 * s0;                              // u_0
    const float2* abp = ab + (size_t)b * NC * H_ + h;
#pragma unroll 8
    for (int cc = 0; cc < c; ++cc) {
        float2 q = abp[(size_t)cc * H_];
        uv = fmaf(q.y, uv, q.x);
    }

    const unsigned* app = AP + ((size_t)b * T_ + c * TC) * H_ + h;
    float* op = out + ((size_t)b * (T_ + 1) + c * TC + 1) * H_ + h;
#pragma unroll 8
    for (int j = 0; j < TC; ++j) {
        unsigned w = app[(size_t)j * H_];
        op[(size_t)j * H_] = fmaf(bf2f((ushort)(w >> 16)), uv, bf2f((ushort)(w & 0xffff)));
    }
}

extern "C" void kernel_launch(void* const* d_in, const int* in_sizes, int n_in,
                              void* d_out, int out_size, void* d_ws, size_t ws_size,
                              hipStream_t stream) {
    const float* inputs = (const float*)d_in[0];   // [B,T,C]
    const float* init_f = (const float*)d_in[1];   // [B,H]
    const float* init_z = (const float*)d_in[2];   // [B,H]
    const float* f_w    = (const float*)d_in[3];   // [H,C,K]
    const float* f_b    = (const float*)d_in[4];   // [H]
    const float* z_w    = (const float*)d_in[5];   // [H,C,K]
    const float* z_b    = (const float*)d_in[6];   // [H]
    float* out = (float*)d_out;                    // [B,T+1,H]

    // ws: wfrag 768KB | AP (B*T*H uint, 32MB) | ab (B*NC*H float2, 2MB)
    ushort* wfrag = (ushort*)d_ws;
    unsigned* AP  = (unsigned*)(wfrag + WFRAG_ELEMS);
    float2* ab    = (float2*)(AP + (size_t)B_ * T_ * H_);

    wfrag_kernel<<<(WFRAG_ELEMS + 255) / 256, 256, 0, stream>>>(f_w, z_w, wfrag);

    dim3 cgrid(T_ / 64, B_, 1);
    conv_scan_kernel<<<cgrid, 512, 0, stream>>>(inputs, wfrag, f_b, z_b, AP, ab);

    dim3 agrid(NC, B_, 1);
    chainapply_kernel<<<agrid, 256, 0, stream>>>(AP, ab, init_f, init_z, out);
}